// Round 22
// baseline (7943.082 us; speedup 1.0000x reference)
//
#include <hip/hip_runtime.h>
#include <math.h>

// Problem constants (fixed by reference file)
#define NB   512    // N = batch of user pairs
#define MM   254    // M uav nodes
#define SS   256    // S = M + 2 graph nodes per b
#define HH   128    // H hidden
#define RTOT 1278   // 2N + M rows in `outputs`
#define NBLK 256    // decode blocks; each handles b and b+256

#define C2   2.885390081777927f   // 2*log2(e): tanh arg pre-scale
#define C1   1.442695040888963f   // log2(e)

__device__ __forceinline__ float rcpf(float x)  { return __builtin_amdgcn_rcpf(x); }
__device__ __forceinline__ float exp2f_(float x){ return __builtin_amdgcn_exp2f(x); }
__device__ __forceinline__ float sigm2(float x) { return rcpf(1.0f + exp2f_(-C1 * x)); }
__device__ __forceinline__ float tanh2(float x) { return 1.0f - 2.0f * rcpf(1.0f + exp2f_(C2 * x)); }

// pos is 2-D, so e = pos@Wemb+bemb is rank-2 in (px,py); therefore
//   EWi[r][j] = px*Ai[j] + py*Bi[j] + Ci[j]          (Ci includes lstm_b)
//   C2*W1e[r][h] = px*A1s[h] + py*B1s[h] + C1s[h]    (pre-scaled by C2)
// coef layout: Ai[512] Bi[512] Ci[512] A1s[128] B1s[128] C1s[128]
__global__ __launch_bounds__(512) void coef_k(
    const float* __restrict__ Wemb, const float* __restrict__ bemb,
    const float* __restrict__ Wi, const float* __restrict__ W1,
    const float* __restrict__ lb, float* __restrict__ coef)
{
  int j = threadIdx.x;  // 0..511
  float a = 0.f, b = 0.f, c = 0.f;
#pragma unroll 8
  for (int h = 0; h < HH; ++h) {
    float w = Wi[(size_t)h * 512 + j];
    a = fmaf(Wemb[h], w, a);
    b = fmaf(Wemb[HH + h], w, b);
    c = fmaf(bemb[h], w, c);
  }
  coef[j] = a; coef[512 + j] = b; coef[1024 + j] = c + lb[j];
  if (j < HH) {
    float a1 = 0.f, b1 = 0.f, c1 = 0.f;
#pragma unroll 8
    for (int h = 0; h < HH; ++h) {
      float w = W1[(size_t)h * HH + j];
      a1 = fmaf(Wemb[h], w, a1);
      b1 = fmaf(Wemb[HH + h], w, b1);
      c1 = fmaf(bemb[h], w, c1);
    }
    coef[1536 + j] = C2 * a1; coef[1664 + j] = C2 * b1; coef[1792 + j] = C2 * c1;
  }
}

// WhT[512][128] = Wh^T, W2T[128][128] = W2^T (per-thread-row float4 reads)
__global__ __launch_bounds__(128) void transpose_k(
    const float* __restrict__ Wh, const float* __restrict__ W2,
    float* __restrict__ WhT, float* __restrict__ W2T)
{
  int bidx = blockIdx.x;  // 0..639
  int k = threadIdx.x;    // 0..127
  if (bidx < 512) WhT[(size_t)bidx * 128 + k] = Wh[(size_t)k * 512 + bidx];
  else {
    int j = bidx - 512;
    W2T[(size_t)j * 128 + k] = W2[(size_t)k * 128 + j];
  }
}

// One block per TWO batch elements. 1024 threads = two 512-thread TEAMS.
// Team g runs b = bid + g*256 through A->B->C->E->F, offset 2 stages vs the
// other team in the same barrier stream: each barrier interval pairs a fat
// phase of one team with a thin/latency phase of the other, so E's VALU
// work fills A's global-load stalls and fat phases cover B/F's idle waves.
// (r14 skeleton, proven correct; its L2-thrash killer — the big gather
// tables — is gone in the rank-2 coef formulation. LDS = 157.7 KB.)
__global__ __attribute__((amdgpu_waves_per_eu(4, 4)))
__launch_bounds__(1024) void decode_k(
    const float* __restrict__ outputs, const float* __restrict__ WhT,
    const float* __restrict__ Wh, const float* __restrict__ W2T,
    const float* __restrict__ av, const float* __restrict__ coef,
    float* __restrict__ maxd_out)
{
  const int t = threadIdx.x;       // 0..1023
  const int bid = blockIdx.x;
  const int team  = t >> 9;        // 0/1
  const int local = t & 511;
  const int g = team;

  __shared__ float WhL[64][512];            // 128 KB: Wh rows 64..127
  __shared__ float posU[2 * MM];            // uav node positions
  __shared__ float dstS[2][2];              // per-g dst node position
  __shared__ float curP[2][2];              // per-g current node position
  __shared__ __align__(16) float hS[2][HH];
  __shared__ __align__(16) float qC[2][HH]; // C2*q + C1s
  __shared__ float C1sS[HH];
  __shared__ __align__(16) float A1sS[HH], B1sS[HH], vS2[HH];
  __shared__ __align__(16) float AiS[512], BiS[512], CiS[512];
  __shared__ __align__(16) float gS[2][512]; // full gates (Wh part)
  __shared__ float lp[2][4][SS];            // logit partials [g][hquarter][u]
  __shared__ int   actS[2][254];
  __shared__ int   cntS[2];

  // phase-local index maps (within team)
  const int cj  = (local >> 2) & 127; // C: q column
  const int ckq = local & 3;          // C: k-quarter
  const int lhq = (local >> 7) & 3;   // E: h-quarter (32 h)
  const int lu  = local & 127;        // E: base node slot (u, u+128)

  // ---- init (all 1024 threads) ----
  for (int i = t; i < 64 * 512; i += 1024) ((float*)WhL)[i] = Wh[64 * 512 + i];
  for (int i = t; i < 2 * MM; i += 1024)   posU[i] = outputs[4 * NB + i];
  if (t < HH) {
    C1sS[t] = coef[1792 + t];
    A1sS[t] = coef[1536 + t];
    B1sS[t] = coef[1664 + t];
    vS2[t]  = -2.0f * av[t];
  }
  if (t < 512) { AiS[t] = coef[t]; BiS[t] = coef[512 + t]; CiS[t] = coef[1024 + t]; }
  if (t < 256) { int gg = t >> 7, j = t & 127; hS[gg][j] = 0.f; }
  if (t < 254) actS[0][t] = t + 1;
  else if (t >= 512 && t < 766) actS[1][t - 512] = t - 511;
  if (t == 0) {
    cntS[0] = 254;
    dstS[0][0] = outputs[2 * (NB + bid)]; dstS[0][1] = outputs[2 * (NB + bid) + 1];
    curP[0][0] = outputs[2 * bid];        curP[0][1] = outputs[2 * bid + 1];
  }
  if (t == 512) {
    cntS[1] = 254;
    dstS[1][0] = outputs[2 * (NB + bid + NBLK)];
    dstS[1][1] = outputs[2 * (NB + bid + NBLK) + 1];
    curP[1][0] = outputs[2 * (bid + NBLK)];
    curP[1][1] = outputs[2 * (bid + NBLK) + 1];
  }
  __syncthreads();

  float px = 0.f, py = 0.f, md = 0.f;   // live in local==0 of each team
  if (local == 0) {
    int b = bid + (g << 8);
    px = outputs[2 * b]; py = outputs[2 * b + 1];
  }

  float creg = 0.f;                     // c-state, owned by local<128

  // pipeline position: team0 starts at phase 0, team1 two stages behind
  int ph = (team == 0) ? 0 : -2;
  int lk = 0;

  const int NSTAGE = 5 * SS + 2;
  for (int sg = 0; sg < NSTAGE; ++sg) {
    bool valid = (ph >= 0) && (lk < SS);
    if (valid) {
      if (ph == 0) {
        // ---- A: gates (Wh part), full sum per thread for column j=local.
        // k 0..63 from WhT row j (4 bursts of 4 float4); k 64..127 from WhL
        // (scalar column reads, 2 lanes/bank = free).
        int j = local;
        const float4* wg4 = (const float4*)(WhT + (size_t)j * 128);
        const float*  wl  = &WhL[0][j];
        const float4* hg4 = (const float4*)(&hS[g][0]);
        const float4* hl4 = (const float4*)(&hS[g][64]);
        float aG = 0.f, aG2 = 0.f, aL = 0.f, aL2 = 0.f;
#pragma unroll
        for (int b = 0; b < 4; ++b) {
          float4 wb[4];
#pragma unroll
          for (int i = 0; i < 4; ++i) wb[i] = wg4[b * 4 + i];
#pragma unroll
          for (int i = 0; i < 4; ++i) {
            float4 h = hg4[b * 4 + i];
            aG  = fmaf(h.x, wb[i].x, aG);  aG2 = fmaf(h.y, wb[i].y, aG2);
            aG  = fmaf(h.z, wb[i].z, aG);  aG2 = fmaf(h.w, wb[i].w, aG2);
          }
        }
#pragma unroll 4
        for (int i = 0; i < 16; ++i) {
          float4 h = hl4[i];
          float w0 = wl[(size_t)(4 * i + 0) * 512];
          float w1 = wl[(size_t)(4 * i + 1) * 512];
          float w2 = wl[(size_t)(4 * i + 2) * 512];
          float w3 = wl[(size_t)(4 * i + 3) * 512];
          aL  = fmaf(h.x, w0, aL);  aL2 = fmaf(h.y, w1, aL2);
          aL  = fmaf(h.z, w2, aL);  aL2 = fmaf(h.w, w3, aL2);
        }
        gS[g][j] = (aG + aG2) + (aL + aL2);
      } else if (ph == 1) {
        // ---- B: LSTM cell (local<128; order i,f,g,o); EWi from rank-2 coef
        if (local < 128) {
          int jj = local;
          float pxc = curP[g][0], pyc = curP[g][1];
          float ei = fmaf(pxc, AiS[jj],       fmaf(pyc, BiS[jj],       CiS[jj]))       + gS[g][jj];
          float ef = fmaf(pxc, AiS[128 + jj], fmaf(pyc, BiS[128 + jj], CiS[128 + jj])) + gS[g][128 + jj];
          float eg2 = fmaf(pxc, AiS[256 + jj], fmaf(pyc, BiS[256 + jj], CiS[256 + jj])) + gS[g][256 + jj];
          float eo = fmaf(pxc, AiS[384 + jj], fmaf(pyc, BiS[384 + jj], CiS[384 + jj])) + gS[g][384 + jj];
          float iv = sigm2(ei), fv = sigm2(ef), gv = tanh2(eg2), ov = sigm2(eo);
          float cn = fv * creg + iv * gv;
          creg = cn;
          hS[g][jj] = ov * tanh2(cn);
        }
      } else if (ph == 2) {
        // ---- C: q[g][j], quad k-split + shfl reduce; fold C1s in
        const float4* w4 = (const float4*)(W2T + (size_t)cj * 128 + ckq * 32);
        const float4* h4 = (const float4*)(&hS[g][ckq * 32]);
        float p0 = 0.f, p1 = 0.f;
#pragma unroll
        for (int i = 0; i < 8; ++i) {
          float4 w = w4[i], h = h4[i];
          p0 = fmaf(h.x, w.x, p0); p1 = fmaf(h.y, w.y, p1);
          p0 = fmaf(h.z, w.z, p0); p1 = fmaf(h.w, w.w, p1);
        }
        float p = p0 + p1;
        p += __shfl_xor(p, 1);
        p += __shfl_xor(p, 2);
        if (ckq == 0) qC[g][cj] = fmaf(C2, p, C1sS[cj]);
      } else if (ph == 3) {
        // ---- E: logits; 4-way h-quarter, 2 nodes/thread; constants shared
        // by both nodes; gathers hoisted. arg = px*A1s + py*B1s + qC.
        int cnt = cntS[g];
        int cntEff = cnt + (lk > 0 ? 1 : 0);
        int u0 = lu, u1 = lu + 128;
        bool e0 = u0 < cntEff, e1 = u1 < cntEff;
        float px0 = 0.f, py0 = 0.f, px1 = 0.f, py1 = 0.f;
        if (e0) {
          int s0 = (u0 == cnt) ? 255 : actS[g][u0];
          if (s0 == 255) { px0 = dstS[g][0]; py0 = dstS[g][1]; }
          else           { px0 = posU[2 * (s0 - 1)]; py0 = posU[2 * (s0 - 1) + 1]; }
        }
        if (e1) {
          int s1 = (u1 == cnt) ? 255 : actS[g][u1];
          if (s1 == 255) { px1 = dstS[g][0]; py1 = dstS[g][1]; }
          else           { px1 = posU[2 * (s1 - 1)]; py1 = posU[2 * (s1 - 1) + 1]; }
        }
        const float4* a14 = (const float4*)(&A1sS[lhq * 32]);
        const float4* b14 = (const float4*)(&B1sS[lhq * 32]);
        const float4* qc4 = (const float4*)(&qC[g][lhq * 32]);
        const float4* vv4 = (const float4*)(&vS2[lhq * 32]);
        float c00 = 0.f, c01 = 0.f, c10 = 0.f, c11 = 0.f;
#pragma unroll 4
        for (int i = 0; i < 8; ++i) {
          float4 a = a14[i], b = b14[i], qc = qc4[i], v = vv4[i];
          if (e0) {
            c00 = fmaf(v.x, rcpf(1.0f + exp2f_(fmaf(px0, a.x, fmaf(py0, b.x, qc.x)))), c00);
            c01 = fmaf(v.y, rcpf(1.0f + exp2f_(fmaf(px0, a.y, fmaf(py0, b.y, qc.y)))), c01);
            c00 = fmaf(v.z, rcpf(1.0f + exp2f_(fmaf(px0, a.z, fmaf(py0, b.z, qc.z)))), c00);
            c01 = fmaf(v.w, rcpf(1.0f + exp2f_(fmaf(px0, a.w, fmaf(py0, b.w, qc.w)))), c01);
          }
          if (e1) {
            c10 = fmaf(v.x, rcpf(1.0f + exp2f_(fmaf(px1, a.x, fmaf(py1, b.x, qc.x)))), c10);
            c11 = fmaf(v.y, rcpf(1.0f + exp2f_(fmaf(px1, a.y, fmaf(py1, b.y, qc.y)))), c11);
            c10 = fmaf(v.z, rcpf(1.0f + exp2f_(fmaf(px1, a.z, fmaf(py1, b.z, qc.z)))), c10);
            c11 = fmaf(v.w, rcpf(1.0f + exp2f_(fmaf(px1, a.w, fmaf(py1, b.w, qc.w)))), c11);
          }
        }
        if (e0) lp[g][lhq][u0] = c00 + c01;
        if (e1) lp[g][lhq][u1] = c10 + c11;
      } else {
        // ---- F: argmax + state update (wave 0 of team)
        if (local < 64) {
          int lane = local;
          int cnt = cntS[g];
          int cntEff = cnt + (lk > 0 ? 1 : 0);
          float val = -INFINITY;
          unsigned key = 0xFFFFFFFFu;
#pragma unroll 2
          for (int c = 0; c < 4; ++c) {
            int u = lane + 64 * c;
            if (u < cntEff) {
              float v2 = (lp[g][0][u] + lp[g][1][u]) + (lp[g][2][u] + lp[g][3][u]);
              int s = (u == cnt) ? 255 : actS[g][u];
              unsigned k2 = ((unsigned)s << 16) | (unsigned)u;
              if (v2 > val || (v2 == val && k2 < key)) { val = v2; key = k2; }
            }
          }
#pragma unroll
          for (int off = 1; off < 64; off <<= 1) {
            float v2 = __shfl_xor(val, off);
            unsigned k2 = __shfl_xor(key, off);
            if (v2 > val || (v2 == val && k2 < key)) { val = v2; key = k2; }
          }
          if (lane == 0) {
            int s   = (int)(key >> 16);
            int pos = (int)(key & 0xFFFFu);
            float nx, ny;
            if (s == 255) { nx = dstS[g][0]; ny = dstS[g][1]; }
            else          { nx = posU[2 * (s - 1)]; ny = posU[2 * (s - 1) + 1]; }
            float dx = nx - px, dy = ny - py;
            float d = sqrtf(dx * dx + dy * dy + 1e-12f);
            if (d > md) md = d;
            px = nx; py = ny;
            curP[g][0] = nx; curP[g][1] = ny;
            if (s != 255) { actS[g][pos] = actS[g][cnt - 1]; cntS[g] = cnt - 1; }
          }
        }
      }
    }
    // advance this team's pipeline position
    ++ph;
    if (ph == 5) { ph = 0; ++lk; }
    __syncthreads();
  }

  if (local == 0) maxd_out[bid + (g << 8)] = md;
}

__global__ __launch_bounds__(512) void reduce_k(const float* __restrict__ maxd,
                                               float* __restrict__ out)
{
  __shared__ float s[512];
  int t = threadIdx.x;
  s[t] = maxd[t];
  __syncthreads();
  for (int off = 256; off > 0; off >>= 1) {
    if (t < off) s[t] += s[t + off];
    __syncthreads();
  }
  if (t == 0) out[0] = s[0] * (1.0f / 512.0f);
}

extern "C" void kernel_launch(void* const* d_in, const int* in_sizes, int n_in,
                              void* d_out, int out_size, void* d_ws, size_t ws_size,
                              hipStream_t stream) {
  const float* outputs = (const float*)d_in[0];
  const float* Wemb    = (const float*)d_in[1];
  const float* bemb    = (const float*)d_in[2];
  const float* Wi      = (const float*)d_in[3];
  const float* Wh      = (const float*)d_in[4];
  const float* lb      = (const float*)d_in[5];
  const float* W1      = (const float*)d_in[6];
  const float* W2      = (const float*)d_in[7];
  const float* av      = (const float*)d_in[8];
  // d_in[9] = N (known constant 512)

  float* ws   = (float*)d_ws;
  float* coef = ws;                        // 1920 floats
  float* WhT  = coef + 2048;               // 512*128
  float* W2T  = WhT + (size_t)512 * 128;   // 128*128
  float* maxd = W2T + (size_t)128 * 128;   // 512

  hipLaunchKernelGGL(coef_k, dim3(1), dim3(512), 0, stream,
                     Wemb, bemb, Wi, W1, lb, coef);
  hipLaunchKernelGGL(transpose_k, dim3(640), dim3(128), 0, stream, Wh, W2, WhT, W2T);
  hipLaunchKernelGGL(decode_k, dim3(NBLK), dim3(1024), 0, stream,
                     outputs, WhT, Wh, W2T, av, coef, maxd);
  hipLaunchKernelGGL(reduce_k, dim3(1), dim3(512), 0, stream, maxd, (float*)d_out);
}

// Round 23
// 2192.733 us; speedup vs baseline: 3.6225x; 3.6225x over previous
//
#include <hip/hip_runtime.h>
#include <math.h>

// Problem constants (fixed by reference file)
#define NB   512    // N = batch of user pairs
#define MM   254    // M uav nodes
#define SS   256    // S = M + 2 graph nodes per b
#define HH   128    // H hidden
#define RTOT 1278   // 2N + M rows in `outputs`
#define NBLK 256    // decode blocks; each handles b and b+256

#define C2   2.885390081777927f   // 2*log2(e): tanh arg pre-scale
#define C1   1.442695040888963f   // log2(e)

__device__ __forceinline__ float rcpf(float x)  { return __builtin_amdgcn_rcpf(x); }
__device__ __forceinline__ float exp2f_(float x){ return __builtin_amdgcn_exp2f(x); }
__device__ __forceinline__ float sigm2(float x) { return rcpf(1.0f + exp2f_(-C1 * x)); }
__device__ __forceinline__ float tanh2(float x) { return 1.0f - 2.0f * rcpf(1.0f + exp2f_(C2 * x)); }

// pos is 2-D, so e = pos@Wemb+bemb is rank-2 in (px,py); therefore
//   EWi[r][j] = px*Ai[j] + py*Bi[j] + Ci[j]          (Ci includes lstm_b)
//   C2*W1e[r][h] = px*A1s[h] + py*B1s[h] + C1s[h]    (pre-scaled by C2)
// coef layout: Ai[512] Bi[512] Ci[512] A1s[128] B1s[128] C1s[128]
__global__ __launch_bounds__(512) void coef_k(
    const float* __restrict__ Wemb, const float* __restrict__ bemb,
    const float* __restrict__ Wi, const float* __restrict__ W1,
    const float* __restrict__ lb, float* __restrict__ coef)
{
  int j = threadIdx.x;  // 0..511
  float a = 0.f, b = 0.f, c = 0.f;
#pragma unroll 8
  for (int h = 0; h < HH; ++h) {
    float w = Wi[(size_t)h * 512 + j];
    a = fmaf(Wemb[h], w, a);
    b = fmaf(Wemb[HH + h], w, b);
    c = fmaf(bemb[h], w, c);
  }
  coef[j] = a; coef[512 + j] = b; coef[1024 + j] = c + lb[j];
  if (j < HH) {
    float a1 = 0.f, b1 = 0.f, c1 = 0.f;
#pragma unroll 8
    for (int h = 0; h < HH; ++h) {
      float w = W1[(size_t)h * HH + j];
      a1 = fmaf(Wemb[h], w, a1);
      b1 = fmaf(Wemb[HH + h], w, b1);
      c1 = fmaf(bemb[h], w, c1);
    }
    coef[1536 + j] = C2 * a1; coef[1664 + j] = C2 * b1; coef[1792 + j] = C2 * c1;
  }
}

// WhT[512][128] = Wh^T, W2T[128][128] = W2^T (per-thread-row float4 reads)
__global__ __launch_bounds__(128) void transpose_k(
    const float* __restrict__ Wh, const float* __restrict__ W2,
    float* __restrict__ WhT, float* __restrict__ W2T)
{
  int bidx = blockIdx.x;  // 0..639
  int k = threadIdx.x;    // 0..127
  if (bidx < 512) WhT[(size_t)bidx * 128 + k] = Wh[(size_t)k * 512 + bidx];
  else {
    int j = bidx - 512;
    W2T[(size_t)j * 128 + k] = W2[(size_t)k * 128 + j];
  }
}

// One block per TWO batch elements (b, b+256). 1024 threads, grid 256.
// r21 base (proven no-spill, 2122 us) + cross-step software pipeline:
// A(k+1) depends only on hS(k), so it runs in E(k)'s barrier interval
// (A' first: global loads issue, then E's transcendental stream hides the
// latency; waves drift freely inside the interval). Barriers 5 -> 4/step.
__global__ __attribute__((amdgpu_waves_per_eu(4, 4)))
__launch_bounds__(1024) void decode_k(
    const float* __restrict__ outputs, const float* __restrict__ WhT,
    const float* __restrict__ Wh, const float* __restrict__ W2T,
    const float* __restrict__ av, const float* __restrict__ coef,
    float* __restrict__ maxd_out)
{
  const int t = threadIdx.x;   // 0..1023
  const int bid = blockIdx.x;

  __shared__ float WhL[64][512];            // 128 KB: Wh rows 64..127
  __shared__ float posU[2 * MM];            // uav node positions
  __shared__ float dstS[2][2];              // per-g dst node position
  __shared__ float curP[2][2];              // per-g current node position
  __shared__ __align__(16) float hS[2][HH];
  __shared__ __align__(16) float qC[2][HH]; // C2*q + C1s
  __shared__ float C1sS[HH];
  __shared__ __align__(16) float A1sS[HH], B1sS[HH], vS2[HH];
  __shared__ __align__(16) float AiS[512], BiS[512], CiS[512];
  __shared__ float pS[2][2][512];           // gates partials [g][gh][j]
  __shared__ float lp[2][4][SS];            // logit partials [g][hquarter][u]
  __shared__ int   actS[2][254];
  __shared__ int   cntS[2];

  // Bank-conflict-free gates mapping: within each 32-lane group gh is
  // uniform and gj covers 32 consecutive values (banks 0..31 distinct).
  const int gh  = (t >> 5) & 1;            // gates k-half (0/1)
  const int gj  = ((t >> 6) << 5) | (t & 31);  // gates column, 0..511
  const int cg  = t >> 9;        // q batch slot
  const int cj  = (t >> 2) & 127;// q column
  const int ckq = t & 3;         // q k-quarter
  const int lg  = t >> 9;        // logits batch slot
  const int lhq = (t >> 7) & 3;  // logits h-quarter (32 h)
  const int lu  = t & 127;       // logits base node slot (u, u+128)

  // ---- init ----
  for (int i = t; i < 64 * 512; i += 1024) ((float*)WhL)[i] = Wh[64 * 512 + i];
  for (int i = t; i < 2 * MM; i += 1024)   posU[i] = outputs[4 * NB + i];
  if (t < HH) {
    C1sS[t] = coef[1792 + t];
    A1sS[t] = coef[1536 + t];
    B1sS[t] = coef[1664 + t];
    vS2[t]  = -2.0f * av[t];
  }
  if (t < 512) { AiS[t] = coef[t]; BiS[t] = coef[512 + t]; CiS[t] = coef[1024 + t]; }
  if (t < 256) { int gg = t >> 7, j = t & 127; hS[gg][j] = 0.f; }
  if (t < 254) actS[0][t] = t + 1;
  else if (t >= 512 && t < 766) actS[1][t - 512] = t - 511;
  if (t == 0) {
    cntS[0] = 254;
    dstS[0][0] = outputs[2 * (NB + bid)]; dstS[0][1] = outputs[2 * (NB + bid) + 1];
    curP[0][0] = outputs[2 * bid];        curP[0][1] = outputs[2 * bid + 1];
  }
  if (t == 512) {
    cntS[1] = 254;
    dstS[1][0] = outputs[2 * (NB + bid + NBLK)];
    dstS[1][1] = outputs[2 * (NB + bid + NBLK) + 1];
    curP[1][0] = outputs[2 * (bid + NBLK)];
    curP[1][1] = outputs[2 * (bid + NBLK) + 1];
  }
  __syncthreads();

  float px = 0.f, py = 0.f, md = 0.f;   // live in t==0 (g0) and t==512 (g1)
  if (t == 0)   { px = curP[0][0]; py = curP[0][1]; }
  if (t == 512) { px = curP[1][0]; py = curP[1][1]; }

  float creg = 0.f;                     // LSTM c-state, owned by t<256

  // ---- Phase A body (computes pS from current hS) ----
  auto phaseA = [&]() {
    const float4* wg4 = (const float4*)(WhT + (size_t)gj * 128 + gh * 32);
    const float*  wl  = &WhL[gh * 32][gj];
    const float4* hb0g = (const float4*)(&hS[0][gh * 32]);
    const float4* hb1g = (const float4*)(&hS[1][gh * 32]);
    const float4* hb0l = (const float4*)(&hS[0][64 + gh * 32]);
    const float4* hb1l = (const float4*)(&hS[1][64 + gh * 32]);
    float a0G = 0.f, a1G = 0.f, a0L = 0.f, a1L = 0.f;
    float4 wb[4];
    // burst 1 (k offsets 0..15)
#pragma unroll
    for (int i = 0; i < 4; ++i) wb[i] = wg4[i];
    // LDS half part 1 while burst 1 is in flight
#pragma unroll
    for (int i = 0; i < 4; ++i) {
      float4 h0 = hb0l[i], h1 = hb1l[i];
      float wa = wl[(size_t)(4 * i) * 512];
      float wbv = wl[(size_t)(4 * i + 1) * 512];
      float wc = wl[(size_t)(4 * i + 2) * 512];
      float wd = wl[(size_t)(4 * i + 3) * 512];
      a0L = fmaf(h0.x, wa, a0L); a0L = fmaf(h0.y, wbv, a0L);
      a0L = fmaf(h0.z, wc, a0L); a0L = fmaf(h0.w, wd, a0L);
      a1L = fmaf(h1.x, wa, a1L); a1L = fmaf(h1.y, wbv, a1L);
      a1L = fmaf(h1.z, wc, a1L); a1L = fmaf(h1.w, wd, a1L);
    }
    // consume burst 1 (h indices gh*32 + 0..15)
#pragma unroll
    for (int i = 0; i < 4; ++i) {
      float4 h0 = hb0g[i], h1 = hb1g[i], w = wb[i];
      a0G = fmaf(h0.x, w.x, a0G); a0G = fmaf(h0.y, w.y, a0G);
      a0G = fmaf(h0.z, w.z, a0G); a0G = fmaf(h0.w, w.w, a0G);
      a1G = fmaf(h1.x, w.x, a1G); a1G = fmaf(h1.y, w.y, a1G);
      a1G = fmaf(h1.z, w.z, a1G); a1G = fmaf(h1.w, w.w, a1G);
    }
    // burst 2 (k offsets 16..31)
#pragma unroll
    for (int i = 0; i < 4; ++i) wb[i] = wg4[4 + i];
    // LDS half part 2 while burst 2 is in flight
#pragma unroll
    for (int i = 4; i < 8; ++i) {
      float4 h0 = hb0l[i], h1 = hb1l[i];
      float wa = wl[(size_t)(4 * i) * 512];
      float wbv = wl[(size_t)(4 * i + 1) * 512];
      float wc = wl[(size_t)(4 * i + 2) * 512];
      float wd = wl[(size_t)(4 * i + 3) * 512];
      a0L = fmaf(h0.x, wa, a0L); a0L = fmaf(h0.y, wbv, a0L);
      a0L = fmaf(h0.z, wc, a0L); a0L = fmaf(h0.w, wd, a0L);
      a1L = fmaf(h1.x, wa, a1L); a1L = fmaf(h1.y, wbv, a1L);
      a1L = fmaf(h1.z, wc, a1L); a1L = fmaf(h1.w, wd, a1L);
    }
    // consume burst 2 (h indices gh*32 + 16..31)
#pragma unroll
    for (int i = 0; i < 4; ++i) {
      float4 h0 = hb0g[4 + i], h1 = hb1g[4 + i], w = wb[i];
      a0G = fmaf(h0.x, w.x, a0G); a0G = fmaf(h0.y, w.y, a0G);
      a0G = fmaf(h0.z, w.z, a0G); a0G = fmaf(h0.w, w.w, a0G);
      a1G = fmaf(h1.x, w.x, a1G); a1G = fmaf(h1.y, w.y, a1G);
      a1G = fmaf(h1.z, w.z, a1G); a1G = fmaf(h1.w, w.w, a1G);
    }
    pS[0][gh][gj] = a0G + a0L;
    pS[1][gh][gj] = a1G + a1L;
  };

  // ---- Prologue: A(0) ----
  phaseA();
  __syncthreads();

  for (int k = 0; k < SS; ++k) {
    // ---- Phase B: LSTM cell (t<256; order i,f,g,o); EWi from LDS coef
    if (t < 256) {
      int g = t >> 7, jj = t & 127;
      float pxc = curP[g][0], pyc = curP[g][1];
      float ei = fmaf(pxc, AiS[jj],       fmaf(pyc, BiS[jj],       CiS[jj]))       + (pS[g][0][jj]       + pS[g][1][jj]);
      float ef = fmaf(pxc, AiS[128 + jj], fmaf(pyc, BiS[128 + jj], CiS[128 + jj])) + (pS[g][0][128 + jj] + pS[g][1][128 + jj]);
      float eg2 = fmaf(pxc, AiS[256 + jj], fmaf(pyc, BiS[256 + jj], CiS[256 + jj])) + (pS[g][0][256 + jj] + pS[g][1][256 + jj]);
      float eo = fmaf(pxc, AiS[384 + jj], fmaf(pyc, BiS[384 + jj], CiS[384 + jj])) + (pS[g][0][384 + jj] + pS[g][1][384 + jj]);
      float iv = sigm2(ei), fv = sigm2(ef), gv = tanh2(eg2), ov = sigm2(eo);
      float cn = fv * creg + iv * gv;
      creg = cn;
      hS[g][jj] = ov * tanh2(cn);
    }
    __syncthreads();  // B1

    // ---- Phase C: q[g][j], quad k-split + shfl reduce; fold C1s in
    {
      const float4* w4 = (const float4*)(W2T + (size_t)cj * 128 + ckq * 32);
      const float4* h4 = (const float4*)(&hS[cg][ckq * 32]);
      float p0 = 0.f, p1 = 0.f;
#pragma unroll
      for (int i = 0; i < 8; ++i) {
        float4 w = w4[i], h = h4[i];
        p0 = fmaf(h.x, w.x, p0); p1 = fmaf(h.y, w.y, p1);
        p0 = fmaf(h.z, w.z, p0); p1 = fmaf(h.w, w.w, p1);
      }
      float p = p0 + p1;
      p += __shfl_xor(p, 1);
      p += __shfl_xor(p, 2);
      if (ckq == 0) qC[cg][cj] = fmaf(C2, p, C1sS[cj]);
    }
    __syncthreads();  // B2

    // ---- Phase A' (k+1) + Phase E (k) in ONE interval: A's global loads
    // issue first; E's transcendental stream hides their latency; no
    // barrier between, so waves drift. A' reads hS(k) (stable until B(k+1)).
    if (k + 1 < SS) phaseA();
    {
      int cnt = cntS[lg];
      int cntEff = cnt + (k > 0 ? 1 : 0);   // dst node re-enters for k>0
      int u0 = lu, u1 = lu + 128;
      bool e0 = u0 < cntEff, e1 = u1 < cntEff;
      float px0 = 0.f, py0 = 0.f, px1 = 0.f, py1 = 0.f;
      if (e0) {
        int s0 = (u0 == cnt) ? 255 : actS[lg][u0];
        if (s0 == 255) { px0 = dstS[lg][0]; py0 = dstS[lg][1]; }
        else           { px0 = posU[2 * (s0 - 1)]; py0 = posU[2 * (s0 - 1) + 1]; }
      }
      if (e1) {
        int s1 = (u1 == cnt) ? 255 : actS[lg][u1];
        if (s1 == 255) { px1 = dstS[lg][0]; py1 = dstS[lg][1]; }
        else           { px1 = posU[2 * (s1 - 1)]; py1 = posU[2 * (s1 - 1) + 1]; }
      }
      const float4* a14 = (const float4*)(&A1sS[lhq * 32]);
      const float4* b14 = (const float4*)(&B1sS[lhq * 32]);
      const float4* qc4 = (const float4*)(&qC[lg][lhq * 32]);
      const float4* vv4 = (const float4*)(&vS2[lhq * 32]);
      float c00 = 0.f, c01 = 0.f, c10 = 0.f, c11 = 0.f;
#pragma unroll 4
      for (int i = 0; i < 8; ++i) {
        float4 a = a14[i], b = b14[i], qc = qc4[i], v = vv4[i];
        if (e0) {
          c00 = fmaf(v.x, rcpf(1.0f + exp2f_(fmaf(px0, a.x, fmaf(py0, b.x, qc.x)))), c00);
          c01 = fmaf(v.y, rcpf(1.0f + exp2f_(fmaf(px0, a.y, fmaf(py0, b.y, qc.y)))), c01);
          c00 = fmaf(v.z, rcpf(1.0f + exp2f_(fmaf(px0, a.z, fmaf(py0, b.z, qc.z)))), c00);
          c01 = fmaf(v.w, rcpf(1.0f + exp2f_(fmaf(px0, a.w, fmaf(py0, b.w, qc.w)))), c01);
        }
        if (e1) {
          c10 = fmaf(v.x, rcpf(1.0f + exp2f_(fmaf(px1, a.x, fmaf(py1, b.x, qc.x)))), c10);
          c11 = fmaf(v.y, rcpf(1.0f + exp2f_(fmaf(px1, a.y, fmaf(py1, b.y, qc.y)))), c11);
          c10 = fmaf(v.z, rcpf(1.0f + exp2f_(fmaf(px1, a.z, fmaf(py1, b.z, qc.z)))), c10);
          c11 = fmaf(v.w, rcpf(1.0f + exp2f_(fmaf(px1, a.w, fmaf(py1, b.w, qc.w)))), c11);
        }
      }
      if (e0) lp[lg][lhq][u0] = c00 + c01;
      if (e1) lp[lg][lhq][u1] = c10 + c11;
    }
    __syncthreads();  // B3

    // ---- Phase F: argmax + state update (wave 0 -> g0, wave 8 -> g1)
    if ((t < 64) || (t >= 512 && t < 576)) {
      int g = t >> 9;
      int lane = t & 63;
      int cnt = cntS[g];
      int cntEff = cnt + (k > 0 ? 1 : 0);
      float val = -INFINITY;
      unsigned key = 0xFFFFFFFFu;
#pragma unroll 2
      for (int c = 0; c < 4; ++c) {
        int u = lane + 64 * c;
        if (u < cntEff) {
          float v2 = (lp[g][0][u] + lp[g][1][u]) + (lp[g][2][u] + lp[g][3][u]);
          int s = (u == cnt) ? 255 : actS[g][u];
          unsigned k2 = ((unsigned)s << 16) | (unsigned)u;
          if (v2 > val || (v2 == val && k2 < key)) { val = v2; key = k2; }
        }
      }
#pragma unroll
      for (int off = 1; off < 64; off <<= 1) {
        float v2 = __shfl_xor(val, off);
        unsigned k2 = __shfl_xor(key, off);
        if (v2 > val || (v2 == val && k2 < key)) { val = v2; key = k2; }
      }
      if (lane == 0) {
        int s   = (int)(key >> 16);
        int pos = (int)(key & 0xFFFFu);
        float nx, ny;
        if (s == 255) { nx = dstS[g][0]; ny = dstS[g][1]; }
        else          { nx = posU[2 * (s - 1)]; ny = posU[2 * (s - 1) + 1]; }
        float dx = nx - px, dy = ny - py;
        float d = sqrtf(dx * dx + dy * dy + 1e-12f);
        if (d > md) md = d;
        px = nx; py = ny;
        curP[g][0] = nx; curP[g][1] = ny;
        if (s != 255) { actS[g][pos] = actS[g][cnt - 1]; cntS[g] = cnt - 1; }
      }
    }
    __syncthreads();  // B4
  }

  if (t == 0)   maxd_out[bid] = md;
  if (t == 512) maxd_out[bid + NBLK] = md;
}

__global__ __launch_bounds__(512) void reduce_k(const float* __restrict__ maxd,
                                               float* __restrict__ out)
{
  __shared__ float s[512];
  int t = threadIdx.x;
  s[t] = maxd[t];
  __syncthreads();
  for (int off = 256; off > 0; off >>= 1) {
    if (t < off) s[t] += s[t + off];
    __syncthreads();
  }
  if (t == 0) out[0] = s[0] * (1.0f / 512.0f);
}

extern "C" void kernel_launch(void* const* d_in, const int* in_sizes, int n_in,
                              void* d_out, int out_size, void* d_ws, size_t ws_size,
                              hipStream_t stream) {
  const float* outputs = (const float*)d_in[0];
  const float* Wemb    = (const float*)d_in[1];
  const float* bemb    = (const float*)d_in[2];
  const float* Wi      = (const float*)d_in[3];
  const float* Wh      = (const float*)d_in[4];
  const float* lb      = (const float*)d_in[5];
  const float* W1      = (const float*)d_in[6];
  const float* W2      = (const float*)d_in[7];
  const float* av      = (const float*)d_in[8];
  // d_in[9] = N (known constant 512)

  float* ws   = (float*)d_ws;
  float* coef = ws;                        // 1920 floats
  float* WhT  = coef + 2048;               // 512*128
  float* W2T  = WhT + (size_t)512 * 128;   // 128*128
  float* maxd = W2T + (size_t)128 * 128;   // 512

  hipLaunchKernelGGL(coef_k, dim3(1), dim3(512), 0, stream,
                     Wemb, bemb, Wi, W1, lb, coef);
  hipLaunchKernelGGL(transpose_k, dim3(640), dim3(128), 0, stream, Wh, W2, WhT, W2T);
  hipLaunchKernelGGL(decode_k, dim3(NBLK), dim3(1024), 0, stream,
                     outputs, WhT, Wh, W2T, av, coef, maxd);
  hipLaunchKernelGGL(reduce_k, dim3(1), dim3(512), 0, stream, maxd, (float*)d_out);
}